// Round 12
// baseline (405.370 us; speedup 1.0000x reference)
//
#include <hip/hip_runtime.h>
#include <hip/hip_bf16.h>

#define TSZ 2048
#define NCH 8
#define NPIX (TSZ * TSZ)

__device__ __forceinline__ unsigned pack_bf16_rne(float a, float b) {
    unsigned ua = __float_as_uint(a);
    unsigned ub = __float_as_uint(b);
    ua += 0x7fffu + ((ua >> 16) & 1u);   // round-to-nearest-even
    ub += 0x7fffu + ((ub >> 16) & 1u);
    return (ua >> 16) | (ub & 0xffff0000u);
}
__device__ __forceinline__ float blo(unsigned u) { return __uint_as_float(u << 16); }
__device__ __forceinline__ float bhi(unsigned u) { return __uint_as_float(u & 0xffff0000u); }

// ===========================================================================
// Tier 1 (ws >= 256 MiB): quad-duplicated layout. txq[q] = 4 x uint4 = 64 B
// holding the 2x2 clamped corner neighborhood of texel q=(y,x), bf16-packed.
// One ray = one aligned 64B line.
// ===========================================================================
__global__ __launch_bounds__(256) void quad_pack_kernel(
    const float* __restrict__ tex, uint4* __restrict__ txq)
{
    const int q = blockIdx.x * 256 + threadIdx.x;
    const int y = q >> 11;            // /2048
    const int x = q & (TSZ - 1);
    const int x1 = min(x + 1, TSZ - 1);
    const int y1 = min(y + 1, TSZ - 1);
    const size_t o00 = (size_t)y  * TSZ + x;
    const size_t o01 = (size_t)y  * TSZ + x1;
    const size_t o10 = (size_t)y1 * TSZ + x;
    const size_t o11 = (size_t)y1 * TSZ + x1;

    float a[NCH], b[NCH], c[NCH], d[NCH];
#pragma unroll
    for (int ch = 0; ch < NCH; ++ch) {
        const float* __restrict__ p = tex + (size_t)ch * NPIX;
        a[ch] = p[o00];
        b[ch] = p[o01];
        c[ch] = p[o10];
        d[ch] = p[o11];
    }
    uint4* dst = txq + (size_t)q * 4;
    dst[0] = make_uint4(pack_bf16_rne(a[0], a[1]), pack_bf16_rne(a[2], a[3]),
                        pack_bf16_rne(a[4], a[5]), pack_bf16_rne(a[6], a[7]));
    dst[1] = make_uint4(pack_bf16_rne(b[0], b[1]), pack_bf16_rne(b[2], b[3]),
                        pack_bf16_rne(b[4], b[5]), pack_bf16_rne(b[6], b[7]));
    dst[2] = make_uint4(pack_bf16_rne(c[0], c[1]), pack_bf16_rne(c[2], c[3]),
                        pack_bf16_rne(c[4], c[5]), pack_bf16_rne(c[6], c[7]));
    dst[3] = make_uint4(pack_bf16_rne(d[0], d[1]), pack_bf16_rne(d[2], d[3]),
                        pack_bf16_rne(d[4], d[5]), pack_bf16_rne(d[6], d[7]));
}

__global__ __launch_bounds__(256) void gather_quad_kernel(
    const float* __restrict__ uv,
    const float* __restrict__ vd,
    const uint4* __restrict__ txq,   // [NPIX][4] quad-duplicated bf16
    const float* __restrict__ w1, const float* __restrict__ b1,
    const float* __restrict__ w2, const float* __restrict__ b2,
    const float* __restrict__ w3, const float* __restrict__ b3,
    float* __restrict__ out, int B)
{
    __shared__ float sw1[16 * 11];
    __shared__ float sb1[16];
    __shared__ float sw2[16 * 16];
    __shared__ float sb2[16];
    __shared__ float sw3[3 * 16];
    __shared__ float sb3[3];

    const int t = threadIdx.x;
    for (int i = t; i < 16 * 11; i += 256) sw1[i] = w1[i];
    for (int i = t; i < 16 * 16; i += 256) sw2[i] = w2[i];
    for (int i = t; i < 3 * 16;  i += 256) sw3[i] = w3[i];
    if (t < 16) { sb1[t] = b1[t]; sb2[t] = b2[t]; }
    if (t < 3)  { sb3[t] = b3[t]; }
    __syncthreads();

    const int idx = blockIdx.x * 256 + t;
    if (idx >= B) return;

    const float2 uv2 = reinterpret_cast<const float2*>(uv)[idx];
    const float fx = fminf(fmaxf((uv2.x + 1.0f) * 0.5f * (float)(TSZ - 1), 0.0f), (float)(TSZ - 1));
    const float fy = fminf(fmaxf((uv2.y + 1.0f) * 0.5f * (float)(TSZ - 1), 0.0f), (float)(TSZ - 1));
    const float x0f = floorf(fx);
    const float y0f = floorf(fy);
    const float wx = fx - x0f;
    const float wy = fy - y0f;
    const int x0 = (int)x0f;
    const int y0 = (int)y0f;

    const float w00 = (1.0f - wx) * (1.0f - wy);
    const float w01 = wx * (1.0f - wy);
    const float w10 = (1.0f - wx) * wy;
    const float w11 = wx * wy;

    const uint4* qb = txq + ((size_t)y0 * TSZ + x0) * 4;
    const uint4 q00 = qb[0];
    const uint4 q01 = qb[1];
    const uint4 q10 = qb[2];
    const uint4 q11 = qb[3];

    float xin[11];
    xin[0] = blo(q00.x) * w00 + blo(q01.x) * w01 + blo(q10.x) * w10 + blo(q11.x) * w11;
    xin[1] = bhi(q00.x) * w00 + bhi(q01.x) * w01 + bhi(q10.x) * w10 + bhi(q11.x) * w11;
    xin[2] = blo(q00.y) * w00 + blo(q01.y) * w01 + blo(q10.y) * w10 + blo(q11.y) * w11;
    xin[3] = bhi(q00.y) * w00 + bhi(q01.y) * w01 + bhi(q10.y) * w10 + bhi(q11.y) * w11;
    xin[4] = blo(q00.z) * w00 + blo(q01.z) * w01 + blo(q10.z) * w10 + blo(q11.z) * w11;
    xin[5] = bhi(q00.z) * w00 + bhi(q01.z) * w01 + bhi(q10.z) * w10 + bhi(q11.z) * w11;
    xin[6] = blo(q00.w) * w00 + blo(q01.w) * w01 + blo(q10.w) * w10 + blo(q11.w) * w11;
    xin[7] = bhi(q00.w) * w00 + bhi(q01.w) * w01 + bhi(q10.w) * w10 + bhi(q11.w) * w11;
    xin[8]  = vd[3 * (size_t)idx + 0];
    xin[9]  = vd[3 * (size_t)idx + 1];
    xin[10] = vd[3 * (size_t)idx + 2];

    float h1[16];
#pragma unroll
    for (int j = 0; j < 16; ++j) {
        float a = sb1[j];
#pragma unroll
        for (int i = 0; i < 11; ++i) a += xin[i] * sw1[j * 11 + i];
        h1[j] = fmaxf(a, 0.0f);
    }
    float h2[16];
#pragma unroll
    for (int j = 0; j < 16; ++j) {
        float a = sb2[j];
#pragma unroll
        for (int i = 0; i < 16; ++i) a += h1[i] * sw2[j * 16 + i];
        h2[j] = fmaxf(a, 0.0f);
    }
    float rgb[3];
#pragma unroll
    for (int k = 0; k < 3; ++k) {
        float a = sb3[k];
#pragma unroll
        for (int i = 0; i < 16; ++i) a += h2[i] * sw3[k * 16 + i];
        rgb[k] = 1.0f / (1.0f + __expf(-a));
    }

    out[3 * (size_t)idx + 0] = rgb[0];
    out[3 * (size_t)idx + 1] = rgb[1];
    out[3 * (size_t)idx + 2] = rgb[2];
}

// ===========================================================================
// Tier 2 (ws >= 64 MiB): flat bf16 [H,W,C] (16 B/texel), vectorized pack.
// ===========================================================================
__global__ __launch_bounds__(256) void transpose_pack4_kernel(
    const float* __restrict__ tex, uint4* __restrict__ txp)
{
    const int p4 = (blockIdx.x * 256 + threadIdx.x) * 4;
    float4 v[NCH];
#pragma unroll
    for (int c = 0; c < NCH; ++c)
        v[c] = *reinterpret_cast<const float4*>(tex + (size_t)c * NPIX + p4);
    const float* vf = reinterpret_cast<const float*>(v);  // vf[c*4 + i]
#pragma unroll
    for (int i = 0; i < 4; ++i) {
        uint4 qq;
        qq.x = pack_bf16_rne(vf[0 * 4 + i], vf[1 * 4 + i]);
        qq.y = pack_bf16_rne(vf[2 * 4 + i], vf[3 * 4 + i]);
        qq.z = pack_bf16_rne(vf[4 * 4 + i], vf[5 * 4 + i]);
        qq.w = pack_bf16_rne(vf[6 * 4 + i], vf[7 * 4 + i]);
        txp[p4 + i] = qq;
    }
}

__global__ __launch_bounds__(256) void gather_mlp_kernel(
    const float* __restrict__ uv,
    const float* __restrict__ vd,
    const uint4* __restrict__ txp,   // [NPIX] packed bf16 x8
    const float* __restrict__ w1, const float* __restrict__ b1,
    const float* __restrict__ w2, const float* __restrict__ b2,
    const float* __restrict__ w3, const float* __restrict__ b3,
    float* __restrict__ out, int B)
{
    __shared__ float sw1[16 * 11];
    __shared__ float sb1[16];
    __shared__ float sw2[16 * 16];
    __shared__ float sb2[16];
    __shared__ float sw3[3 * 16];
    __shared__ float sb3[3];

    const int t = threadIdx.x;
    for (int i = t; i < 16 * 11; i += 256) sw1[i] = w1[i];
    for (int i = t; i < 16 * 16; i += 256) sw2[i] = w2[i];
    for (int i = t; i < 3 * 16;  i += 256) sw3[i] = w3[i];
    if (t < 16) { sb1[t] = b1[t]; sb2[t] = b2[t]; }
    if (t < 3)  { sb3[t] = b3[t]; }
    __syncthreads();

    const int idx = blockIdx.x * 256 + t;
    if (idx >= B) return;

    const float2 uv2 = reinterpret_cast<const float2*>(uv)[idx];
    const float fx = fminf(fmaxf((uv2.x + 1.0f) * 0.5f * (float)(TSZ - 1), 0.0f), (float)(TSZ - 1));
    const float fy = fminf(fmaxf((uv2.y + 1.0f) * 0.5f * (float)(TSZ - 1), 0.0f), (float)(TSZ - 1));
    const float x0f = floorf(fx);
    const float y0f = floorf(fy);
    const float wx = fx - x0f;
    const float wy = fy - y0f;
    const int x0 = (int)x0f;
    const int y0 = (int)y0f;
    const int x1 = min(x0 + 1, TSZ - 1);
    const int y1 = min(y0 + 1, TSZ - 1);

    const float w00 = (1.0f - wx) * (1.0f - wy);
    const float w01 = wx * (1.0f - wy);
    const float w10 = (1.0f - wx) * wy;
    const float w11 = wx * wy;

    const uint4 q00 = txp[(size_t)y0 * TSZ + x0];
    const uint4 q01 = txp[(size_t)y0 * TSZ + x1];
    const uint4 q10 = txp[(size_t)y1 * TSZ + x0];
    const uint4 q11 = txp[(size_t)y1 * TSZ + x1];

    float xin[11];
    xin[0] = blo(q00.x) * w00 + blo(q01.x) * w01 + blo(q10.x) * w10 + blo(q11.x) * w11;
    xin[1] = bhi(q00.x) * w00 + bhi(q01.x) * w01 + bhi(q10.x) * w10 + bhi(q11.x) * w11;
    xin[2] = blo(q00.y) * w00 + blo(q01.y) * w01 + blo(q10.y) * w10 + blo(q11.y) * w11;
    xin[3] = bhi(q00.y) * w00 + bhi(q01.y) * w01 + bhi(q10.y) * w10 + bhi(q11.y) * w11;
    xin[4] = blo(q00.z) * w00 + blo(q01.z) * w01 + blo(q10.z) * w10 + blo(q11.z) * w11;
    xin[5] = bhi(q00.z) * w00 + bhi(q01.z) * w01 + bhi(q10.z) * w10 + bhi(q11.z) * w11;
    xin[6] = blo(q00.w) * w00 + blo(q01.w) * w01 + blo(q10.w) * w10 + blo(q11.w) * w11;
    xin[7] = bhi(q00.w) * w00 + bhi(q01.w) * w01 + bhi(q10.w) * w10 + bhi(q11.w) * w11;
    xin[8]  = vd[3 * (size_t)idx + 0];
    xin[9]  = vd[3 * (size_t)idx + 1];
    xin[10] = vd[3 * (size_t)idx + 2];

    float h1[16];
#pragma unroll
    for (int j = 0; j < 16; ++j) {
        float a = sb1[j];
#pragma unroll
        for (int i = 0; i < 11; ++i) a += xin[i] * sw1[j * 11 + i];
        h1[j] = fmaxf(a, 0.0f);
    }
    float h2[16];
#pragma unroll
    for (int j = 0; j < 16; ++j) {
        float a = sb2[j];
#pragma unroll
        for (int i = 0; i < 16; ++i) a += h1[i] * sw2[j * 16 + i];
        h2[j] = fmaxf(a, 0.0f);
    }
    float rgb[3];
#pragma unroll
    for (int k = 0; k < 3; ++k) {
        float a = sb3[k];
#pragma unroll
        for (int i = 0; i < 16; ++i) a += h2[i] * sw3[k * 16 + i];
        rgb[k] = 1.0f / (1.0f + __expf(-a));
    }

    out[3 * (size_t)idx + 0] = rgb[0];
    out[3 * (size_t)idx + 1] = rgb[1];
    out[3 * (size_t)idx + 2] = rgb[2];
}

// ===========================================================================
// Tier 3: baseline one-pass kernel (channel-major gather) if ws tiny.
// ===========================================================================
__global__ __launch_bounds__(256) void hybrid_texmlp_kernel(
    const float* __restrict__ uv,
    const float* __restrict__ vd,
    const float* __restrict__ tex,
    const float* __restrict__ w1, const float* __restrict__ b1,
    const float* __restrict__ w2, const float* __restrict__ b2,
    const float* __restrict__ w3, const float* __restrict__ b3,
    float* __restrict__ out, int B)
{
    __shared__ float sw1[16 * 11];
    __shared__ float sb1[16];
    __shared__ float sw2[16 * 16];
    __shared__ float sb2[16];
    __shared__ float sw3[3 * 16];
    __shared__ float sb3[3];

    const int t = threadIdx.x;
    for (int i = t; i < 16 * 11; i += 256) sw1[i] = w1[i];
    for (int i = t; i < 16 * 16; i += 256) sw2[i] = w2[i];
    for (int i = t; i < 3 * 16;  i += 256) sw3[i] = w3[i];
    if (t < 16) { sb1[t] = b1[t]; sb2[t] = b2[t]; }
    if (t < 3)  { sb3[t] = b3[t]; }
    __syncthreads();

    const int idx = blockIdx.x * 256 + t;
    if (idx >= B) return;

    const float2 uv2 = reinterpret_cast<const float2*>(uv)[idx];
    const float fx = fminf(fmaxf((uv2.x + 1.0f) * 0.5f * (float)(TSZ - 1), 0.0f), (float)(TSZ - 1));
    const float fy = fminf(fmaxf((uv2.y + 1.0f) * 0.5f * (float)(TSZ - 1), 0.0f), (float)(TSZ - 1));
    const float x0f = floorf(fx);
    const float y0f = floorf(fy);
    const float wx = fx - x0f;
    const float wy = fy - y0f;
    const int x0 = (int)x0f;
    const int y0 = (int)y0f;
    const int x1 = min(x0 + 1, TSZ - 1);
    const int y1 = min(y0 + 1, TSZ - 1);

    const float w00 = (1.0f - wx) * (1.0f - wy);
    const float w01 = wx * (1.0f - wy);
    const float w10 = (1.0f - wx) * wy;
    const float w11 = wx * wy;

    const size_t o00 = (size_t)y0 * TSZ + x0;
    const size_t o01 = (size_t)y0 * TSZ + x1;
    const size_t o10 = (size_t)y1 * TSZ + x0;
    const size_t o11 = (size_t)y1 * TSZ + x1;

    float xin[11];
#pragma unroll
    for (int c = 0; c < NCH; ++c) {
        const float* __restrict__ p = tex + (size_t)c * NPIX;
        xin[c] = p[o00] * w00 + p[o01] * w01 + p[o10] * w10 + p[o11] * w11;
    }
    xin[8]  = vd[3 * (size_t)idx + 0];
    xin[9]  = vd[3 * (size_t)idx + 1];
    xin[10] = vd[3 * (size_t)idx + 2];

    float h1[16];
#pragma unroll
    for (int j = 0; j < 16; ++j) {
        float a = sb1[j];
#pragma unroll
        for (int i = 0; i < 11; ++i) a += xin[i] * sw1[j * 11 + i];
        h1[j] = fmaxf(a, 0.0f);
    }
    float h2[16];
#pragma unroll
    for (int j = 0; j < 16; ++j) {
        float a = sb2[j];
#pragma unroll
        for (int i = 0; i < 16; ++i) a += h1[i] * sw2[j * 16 + i];
        h2[j] = fmaxf(a, 0.0f);
    }
    float rgb[3];
#pragma unroll
    for (int k = 0; k < 3; ++k) {
        float a = sb3[k];
#pragma unroll
        for (int i = 0; i < 16; ++i) a += h2[i] * sw3[k * 16 + i];
        rgb[k] = 1.0f / (1.0f + __expf(-a));
    }

    out[3 * (size_t)idx + 0] = rgb[0];
    out[3 * (size_t)idx + 1] = rgb[1];
    out[3 * (size_t)idx + 2] = rgb[2];
}

extern "C" void kernel_launch(void* const* d_in, const int* in_sizes, int n_in,
                              void* d_out, int out_size, void* d_ws, size_t ws_size,
                              hipStream_t stream) {
    const float* uv  = (const float*)d_in[0];
    const float* vd  = (const float*)d_in[1];
    const float* tex = (const float*)d_in[2];
    const float* w1  = (const float*)d_in[3];
    const float* b1  = (const float*)d_in[4];
    const float* w2  = (const float*)d_in[5];
    const float* b2  = (const float*)d_in[6];
    const float* w3  = (const float*)d_in[7];
    const float* b3  = (const float*)d_in[8];
    float* out = (float*)d_out;

    const int B = in_sizes[0] / 2;
    const int block = 256;
    const int grid = (B + block - 1) / block;

    const size_t need_quad = (size_t)NPIX * 64;   // 256 MiB quad-duplicated
    const size_t need_flat = (size_t)NPIX * 16;   // 64 MiB flat packed

    if (ws_size >= need_quad) {
        uint4* txq = (uint4*)d_ws;
        quad_pack_kernel<<<NPIX / block, block, 0, stream>>>(tex, txq);
        gather_quad_kernel<<<grid, block, 0, stream>>>(
            uv, vd, txq, w1, b1, w2, b2, w3, b3, out, B);
    } else if (ws_size >= need_flat) {
        uint4* txp = (uint4*)d_ws;
        transpose_pack4_kernel<<<NPIX / (block * 4), block, 0, stream>>>(tex, txp);
        gather_mlp_kernel<<<grid, block, 0, stream>>>(
            uv, vd, txp, w1, b1, w2, b2, w3, b3, out, B);
    } else {
        hybrid_texmlp_kernel<<<grid, block, 0, stream>>>(
            uv, vd, tex, w1, b1, w2, b2, w3, b3, out, B);
    }
}

// Round 14
// 405.038 us; speedup vs baseline: 1.0008x; 1.0008x over previous
//
#include <hip/hip_runtime.h>
#include <hip/hip_bf16.h>

#define TSZ 2048
#define NCH 8
#define NPIX (TSZ * TSZ)

__device__ __forceinline__ unsigned pack_bf16_rne(float a, float b) {
    unsigned ua = __float_as_uint(a);
    unsigned ub = __float_as_uint(b);
    ua += 0x7fffu + ((ua >> 16) & 1u);   // round-to-nearest-even
    ub += 0x7fffu + ((ub >> 16) & 1u);
    return (ua >> 16) | (ub & 0xffff0000u);
}
__device__ __forceinline__ float blo(unsigned u) { return __uint_as_float(u << 16); }
__device__ __forceinline__ float bhi(unsigned u) { return __uint_as_float(u & 0xffff0000u); }

// ===========================================================================
// Tier 1 (ws >= 256 MiB): quad-duplicated layout. txq[p*4+j] = uint4 holding
// the 8 bf16 channels of clamped corner j (dy=j>>1, dx=j&1) of texel p.
// One ray = one aligned 64B line (txq[p*4 .. p*4+3]).
// COALESCED pack: thread g writes exactly txq[g] -> dense dwordx4 stores.
// (Round-12 version wrote 64B per thread -> stride-64B scattered stores,
//  2.0 TB/s effective, 171 us. This version's stores are wave-dense.)
// ===========================================================================
__global__ __launch_bounds__(256) void quad_pack_kernel(
    const float* __restrict__ tex, uint4* __restrict__ txq)
{
    const int g = blockIdx.x * 256 + threadIdx.x;  // 0 .. NPIX*4-1
    const int j = g & 3;                           // corner index
    const int p = g >> 2;                          // texel index
    const int y = p >> 11;                         // /2048
    const int x = p & (TSZ - 1);
    const int xs = min(x + (j & 1), TSZ - 1);
    const int ys = min(y + (j >> 1), TSZ - 1);
    const size_t o = (size_t)ys * TSZ + xs;

    float v[NCH];
#pragma unroll
    for (int c = 0; c < NCH; ++c)
        v[c] = tex[(size_t)c * NPIX + o];

    txq[g] = make_uint4(pack_bf16_rne(v[0], v[1]), pack_bf16_rne(v[2], v[3]),
                        pack_bf16_rne(v[4], v[5]), pack_bf16_rne(v[6], v[7]));
}

__global__ __launch_bounds__(256) void gather_quad_kernel(
    const float* __restrict__ uv,
    const float* __restrict__ vd,
    const uint4* __restrict__ txq,   // [NPIX][4] quad-duplicated bf16
    const float* __restrict__ w1, const float* __restrict__ b1,
    const float* __restrict__ w2, const float* __restrict__ b2,
    const float* __restrict__ w3, const float* __restrict__ b3,
    float* __restrict__ out, int B)
{
    __shared__ float sw1[16 * 11];
    __shared__ float sb1[16];
    __shared__ float sw2[16 * 16];
    __shared__ float sb2[16];
    __shared__ float sw3[3 * 16];
    __shared__ float sb3[3];

    const int t = threadIdx.x;
    for (int i = t; i < 16 * 11; i += 256) sw1[i] = w1[i];
    for (int i = t; i < 16 * 16; i += 256) sw2[i] = w2[i];
    for (int i = t; i < 3 * 16;  i += 256) sw3[i] = w3[i];
    if (t < 16) { sb1[t] = b1[t]; sb2[t] = b2[t]; }
    if (t < 3)  { sb3[t] = b3[t]; }
    __syncthreads();

    const int idx = blockIdx.x * 256 + t;
    if (idx >= B) return;

    const float2 uv2 = reinterpret_cast<const float2*>(uv)[idx];
    const float fx = fminf(fmaxf((uv2.x + 1.0f) * 0.5f * (float)(TSZ - 1), 0.0f), (float)(TSZ - 1));
    const float fy = fminf(fmaxf((uv2.y + 1.0f) * 0.5f * (float)(TSZ - 1), 0.0f), (float)(TSZ - 1));
    const float x0f = floorf(fx);
    const float y0f = floorf(fy);
    const float wx = fx - x0f;
    const float wy = fy - y0f;
    const int x0 = (int)x0f;
    const int y0 = (int)y0f;

    const float w00 = (1.0f - wx) * (1.0f - wy);
    const float w01 = wx * (1.0f - wy);
    const float w10 = (1.0f - wx) * wy;
    const float w11 = wx * wy;

    const uint4* qb = txq + ((size_t)y0 * TSZ + x0) * 4;
    const uint4 q00 = qb[0];
    const uint4 q01 = qb[1];
    const uint4 q10 = qb[2];
    const uint4 q11 = qb[3];

    float xin[11];
    xin[0] = blo(q00.x) * w00 + blo(q01.x) * w01 + blo(q10.x) * w10 + blo(q11.x) * w11;
    xin[1] = bhi(q00.x) * w00 + bhi(q01.x) * w01 + bhi(q10.x) * w10 + bhi(q11.x) * w11;
    xin[2] = blo(q00.y) * w00 + blo(q01.y) * w01 + blo(q10.y) * w10 + blo(q11.y) * w11;
    xin[3] = bhi(q00.y) * w00 + bhi(q01.y) * w01 + bhi(q10.y) * w10 + bhi(q11.y) * w11;
    xin[4] = blo(q00.z) * w00 + blo(q01.z) * w01 + blo(q10.z) * w10 + blo(q11.z) * w11;
    xin[5] = bhi(q00.z) * w00 + bhi(q01.z) * w01 + bhi(q10.z) * w10 + bhi(q11.z) * w11;
    xin[6] = blo(q00.w) * w00 + blo(q01.w) * w01 + blo(q10.w) * w10 + blo(q11.w) * w11;
    xin[7] = bhi(q00.w) * w00 + bhi(q01.w) * w01 + bhi(q10.w) * w10 + bhi(q11.w) * w11;
    xin[8]  = vd[3 * (size_t)idx + 0];
    xin[9]  = vd[3 * (size_t)idx + 1];
    xin[10] = vd[3 * (size_t)idx + 2];

    float h1[16];
#pragma unroll
    for (int j = 0; j < 16; ++j) {
        float a = sb1[j];
#pragma unroll
        for (int i = 0; i < 11; ++i) a += xin[i] * sw1[j * 11 + i];
        h1[j] = fmaxf(a, 0.0f);
    }
    float h2[16];
#pragma unroll
    for (int j = 0; j < 16; ++j) {
        float a = sb2[j];
#pragma unroll
        for (int i = 0; i < 16; ++i) a += h1[i] * sw2[j * 16 + i];
        h2[j] = fmaxf(a, 0.0f);
    }
    float rgb[3];
#pragma unroll
    for (int k = 0; k < 3; ++k) {
        float a = sb3[k];
#pragma unroll
        for (int i = 0; i < 16; ++i) a += h2[i] * sw3[k * 16 + i];
        rgb[k] = 1.0f / (1.0f + __expf(-a));
    }

    out[3 * (size_t)idx + 0] = rgb[0];
    out[3 * (size_t)idx + 1] = rgb[1];
    out[3 * (size_t)idx + 2] = rgb[2];
}

// ===========================================================================
// Tier 2 (ws >= 64 MiB): flat bf16 [H,W,C] (16 B/texel), vectorized pack.
// ===========================================================================
__global__ __launch_bounds__(256) void transpose_pack4_kernel(
    const float* __restrict__ tex, uint4* __restrict__ txp)
{
    const int p4 = (blockIdx.x * 256 + threadIdx.x) * 4;
    float4 v[NCH];
#pragma unroll
    for (int c = 0; c < NCH; ++c)
        v[c] = *reinterpret_cast<const float4*>(tex + (size_t)c * NPIX + p4);
    const float* vf = reinterpret_cast<const float*>(v);  // vf[c*4 + i]
#pragma unroll
    for (int i = 0; i < 4; ++i) {
        uint4 qq;
        qq.x = pack_bf16_rne(vf[0 * 4 + i], vf[1 * 4 + i]);
        qq.y = pack_bf16_rne(vf[2 * 4 + i], vf[3 * 4 + i]);
        qq.z = pack_bf16_rne(vf[4 * 4 + i], vf[5 * 4 + i]);
        qq.w = pack_bf16_rne(vf[6 * 4 + i], vf[7 * 4 + i]);
        txp[p4 + i] = qq;
    }
}

__global__ __launch_bounds__(256) void gather_mlp_kernel(
    const float* __restrict__ uv,
    const float* __restrict__ vd,
    const uint4* __restrict__ txp,   // [NPIX] packed bf16 x8
    const float* __restrict__ w1, const float* __restrict__ b1,
    const float* __restrict__ w2, const float* __restrict__ b2,
    const float* __restrict__ w3, const float* __restrict__ b3,
    float* __restrict__ out, int B)
{
    __shared__ float sw1[16 * 11];
    __shared__ float sb1[16];
    __shared__ float sw2[16 * 16];
    __shared__ float sb2[16];
    __shared__ float sw3[3 * 16];
    __shared__ float sb3[3];

    const int t = threadIdx.x;
    for (int i = t; i < 16 * 11; i += 256) sw1[i] = w1[i];
    for (int i = t; i < 16 * 16; i += 256) sw2[i] = w2[i];
    for (int i = t; i < 3 * 16;  i += 256) sw3[i] = w3[i];
    if (t < 16) { sb1[t] = b1[t]; sb2[t] = b2[t]; }
    if (t < 3)  { sb3[t] = b3[t]; }
    __syncthreads();

    const int idx = blockIdx.x * 256 + t;
    if (idx >= B) return;

    const float2 uv2 = reinterpret_cast<const float2*>(uv)[idx];
    const float fx = fminf(fmaxf((uv2.x + 1.0f) * 0.5f * (float)(TSZ - 1), 0.0f), (float)(TSZ - 1));
    const float fy = fminf(fmaxf((uv2.y + 1.0f) * 0.5f * (float)(TSZ - 1), 0.0f), (float)(TSZ - 1));
    const float x0f = floorf(fx);
    const float y0f = floorf(fy);
    const float wx = fx - x0f;
    const float wy = fy - y0f;
    const int x0 = (int)x0f;
    const int y0 = (int)y0f;
    const int x1 = min(x0 + 1, TSZ - 1);
    const int y1 = min(y0 + 1, TSZ - 1);

    const float w00 = (1.0f - wx) * (1.0f - wy);
    const float w01 = wx * (1.0f - wy);
    const float w10 = (1.0f - wx) * wy;
    const float w11 = wx * wy;

    const uint4 q00 = txp[(size_t)y0 * TSZ + x0];
    const uint4 q01 = txp[(size_t)y0 * TSZ + x1];
    const uint4 q10 = txp[(size_t)y1 * TSZ + x0];
    const uint4 q11 = txp[(size_t)y1 * TSZ + x1];

    float xin[11];
    xin[0] = blo(q00.x) * w00 + blo(q01.x) * w01 + blo(q10.x) * w10 + blo(q11.x) * w11;
    xin[1] = bhi(q00.x) * w00 + bhi(q01.x) * w01 + bhi(q10.x) * w10 + bhi(q11.x) * w11;
    xin[2] = blo(q00.y) * w00 + blo(q01.y) * w01 + blo(q10.y) * w10 + blo(q11.y) * w11;
    xin[3] = bhi(q00.y) * w00 + bhi(q01.y) * w01 + bhi(q10.y) * w10 + bhi(q11.y) * w11;
    xin[4] = blo(q00.z) * w00 + blo(q01.z) * w01 + blo(q10.z) * w10 + blo(q11.z) * w11;
    xin[5] = bhi(q00.z) * w00 + bhi(q01.z) * w01 + bhi(q10.z) * w10 + bhi(q11.z) * w11;
    xin[6] = blo(q00.w) * w00 + blo(q01.w) * w01 + blo(q10.w) * w10 + blo(q11.w) * w11;
    xin[7] = bhi(q00.w) * w00 + bhi(q01.w) * w01 + bhi(q10.w) * w10 + bhi(q11.w) * w11;
    xin[8]  = vd[3 * (size_t)idx + 0];
    xin[9]  = vd[3 * (size_t)idx + 1];
    xin[10] = vd[3 * (size_t)idx + 2];

    float h1[16];
#pragma unroll
    for (int j = 0; j < 16; ++j) {
        float a = sb1[j];
#pragma unroll
        for (int i = 0; i < 11; ++i) a += xin[i] * sw1[j * 11 + i];
        h1[j] = fmaxf(a, 0.0f);
    }
    float h2[16];
#pragma unroll
    for (int j = 0; j < 16; ++j) {
        float a = sb2[j];
#pragma unroll
        for (int i = 0; i < 16; ++i) a += h1[i] * sw2[j * 16 + i];
        h2[j] = fmaxf(a, 0.0f);
    }
    float rgb[3];
#pragma unroll
    for (int k = 0; k < 3; ++k) {
        float a = sb3[k];
#pragma unroll
        for (int i = 0; i < 16; ++i) a += h2[i] * sw3[k * 16 + i];
        rgb[k] = 1.0f / (1.0f + __expf(-a));
    }

    out[3 * (size_t)idx + 0] = rgb[0];
    out[3 * (size_t)idx + 1] = rgb[1];
    out[3 * (size_t)idx + 2] = rgb[2];
}

// ===========================================================================
// Tier 3: baseline one-pass kernel (channel-major gather) if ws tiny.
// ===========================================================================
__global__ __launch_bounds__(256) void hybrid_texmlp_kernel(
    const float* __restrict__ uv,
    const float* __restrict__ vd,
    const float* __restrict__ tex,
    const float* __restrict__ w1, const float* __restrict__ b1,
    const float* __restrict__ w2, const float* __restrict__ b2,
    const float* __restrict__ w3, const float* __restrict__ b3,
    float* __restrict__ out, int B)
{
    __shared__ float sw1[16 * 11];
    __shared__ float sb1[16];
    __shared__ float sw2[16 * 16];
    __shared__ float sb2[16];
    __shared__ float sw3[3 * 16];
    __shared__ float sb3[3];

    const int t = threadIdx.x;
    for (int i = t; i < 16 * 11; i += 256) sw1[i] = w1[i];
    for (int i = t; i < 16 * 16; i += 256) sw2[i] = w2[i];
    for (int i = t; i < 3 * 16;  i += 256) sw3[i] = w3[i];
    if (t < 16) { sb1[t] = b1[t]; sb2[t] = b2[t]; }
    if (t < 3)  { sb3[t] = b3[t]; }
    __syncthreads();

    const int idx = blockIdx.x * 256 + t;
    if (idx >= B) return;

    const float2 uv2 = reinterpret_cast<const float2*>(uv)[idx];
    const float fx = fminf(fmaxf((uv2.x + 1.0f) * 0.5f * (float)(TSZ - 1), 0.0f), (float)(TSZ - 1));
    const float fy = fminf(fmaxf((uv2.y + 1.0f) * 0.5f * (float)(TSZ - 1), 0.0f), (float)(TSZ - 1));
    const float x0f = floorf(fx);
    const float y0f = floorf(fy);
    const float wx = fx - x0f;
    const float wy = fy - y0f;
    const int x0 = (int)x0f;
    const int y0 = (int)y0f;
    const int x1 = min(x0 + 1, TSZ - 1);
    const int y1 = min(y0 + 1, TSZ - 1);

    const float w00 = (1.0f - wx) * (1.0f - wy);
    const float w01 = wx * (1.0f - wy);
    const float w10 = (1.0f - wx) * wy;
    const float w11 = wx * wy;

    const size_t o00 = (size_t)y0 * TSZ + x0;
    const size_t o01 = (size_t)y0 * TSZ + x1;
    const size_t o10 = (size_t)y1 * TSZ + x0;
    const size_t o11 = (size_t)y1 * TSZ + x1;

    float xin[11];
#pragma unroll
    for (int c = 0; c < NCH; ++c) {
        const float* __restrict__ p = tex + (size_t)c * NPIX;
        xin[c] = p[o00] * w00 + p[o01] * w01 + p[o10] * w10 + p[o11] * w11;
    }
    xin[8]  = vd[3 * (size_t)idx + 0];
    xin[9]  = vd[3 * (size_t)idx + 1];
    xin[10] = vd[3 * (size_t)idx + 2];

    float h1[16];
#pragma unroll
    for (int j = 0; j < 16; ++j) {
        float a = sb1[j];
#pragma unroll
        for (int i = 0; i < 11; ++i) a += xin[i] * sw1[j * 11 + i];
        h1[j] = fmaxf(a, 0.0f);
    }
    float h2[16];
#pragma unroll
    for (int j = 0; j < 16; ++j) {
        float a = sb2[j];
#pragma unroll
        for (int i = 0; i < 16; ++i) a += h1[i] * sw2[j * 16 + i];
        h2[j] = fmaxf(a, 0.0f);
    }
    float rgb[3];
#pragma unroll
    for (int k = 0; k < 3; ++k) {
        float a = sb3[k];
#pragma unroll
        for (int i = 0; i < 16; ++i) a += h2[i] * sw3[k * 16 + i];
        rgb[k] = 1.0f / (1.0f + __expf(-a));
    }

    out[3 * (size_t)idx + 0] = rgb[0];
    out[3 * (size_t)idx + 1] = rgb[1];
    out[3 * (size_t)idx + 2] = rgb[2];
}

extern "C" void kernel_launch(void* const* d_in, const int* in_sizes, int n_in,
                              void* d_out, int out_size, void* d_ws, size_t ws_size,
                              hipStream_t stream) {
    const float* uv  = (const float*)d_in[0];
    const float* vd  = (const float*)d_in[1];
    const float* tex = (const float*)d_in[2];
    const float* w1  = (const float*)d_in[3];
    const float* b1  = (const float*)d_in[4];
    const float* w2  = (const float*)d_in[5];
    const float* b2  = (const float*)d_in[6];
    const float* w3  = (const float*)d_in[7];
    const float* b3  = (const float*)d_in[8];
    float* out = (float*)d_out;

    const int B = in_sizes[0] / 2;
    const int block = 256;
    const int grid = (B + block - 1) / block;

    const size_t need_quad = (size_t)NPIX * 64;   // 256 MiB quad-duplicated
    const size_t need_flat = (size_t)NPIX * 16;   // 64 MiB flat packed

    if (ws_size >= need_quad) {
        uint4* txq = (uint4*)d_ws;
        quad_pack_kernel<<<(NPIX * 4) / block, block, 0, stream>>>(tex, txq);
        gather_quad_kernel<<<grid, block, 0, stream>>>(
            uv, vd, txq, w1, b1, w2, b2, w3, b3, out, B);
    } else if (ws_size >= need_flat) {
        uint4* txp = (uint4*)d_ws;
        transpose_pack4_kernel<<<NPIX / (block * 4), block, 0, stream>>>(tex, txp);
        gather_mlp_kernel<<<grid, block, 0, stream>>>(
            uv, vd, txp, w1, b1, w2, b2, w3, b3, out, B);
    } else {
        hybrid_texmlp_kernel<<<grid, block, 0, stream>>>(
            uv, vd, tex, w1, b1, w2, b2, w3, b3, out, B);
    }
}